// Round 6
// baseline (233.495 us; speedup 1.0000x reference)
//
#include <hip/hip_runtime.h>
#include <math.h>

// Problem constants (fixed by setup_inputs)
constexpr int kB  = 16;
constexpr int kC  = 8;
constexpr int kH  = 512;
constexpr int kW  = 512;
constexpr int kNB = 15;
constexpr int kHW = kH * kW;          // 262144
constexpr int kG  = kHW / 4;          // float4 groups per (b,c) plane

// Bit-exact replica of numpy's universal-intrinsics simd_exp_f32 (Cephes-style,
// Cody-Waite reduction, FMA Horner, final fma(poly, r^2, r+1), 2^q scale).
// Valid for x in [-87, 0] (our range: x = logit - max <= 0, > -40).
__device__ __forceinline__ float np_expf(float x) {
    const float log2e = 1.44269504088896341f;      // rounds to 0x3FB8AA3B
    float q = rintf(x * log2e);                    // separate mul, then rint (RNE)
    float r = fmaf(q, -0.693359375f, x);           // Cody-Waite hi
    r = fmaf(q, 2.12194440e-4f, r);                // Cody-Waite lo
    float r2 = r * r;
    float p = fmaf(1.9875691500e-4f, r, 1.3981999507e-3f);
    p = fmaf(p, r, 8.3334519073e-3f);
    p = fmaf(p, r, 4.1665795894e-2f);
    p = fmaf(p, r, 1.6666665459e-1f);
    p = fmaf(p, r, 5.0000001201e-1f);
    p = fmaf(p, r2, r + 1.0f);                     // poly*r^2 + (r + 1)
    return ldexpf(p, (int)q);                      // exact scaling (q in [-60,0])
}

__global__ __launch_bounds__(256)
void hist_calib_kernel(const float* __restrict__ logits,
                       const float* __restrict__ val_freqs,
                       float* __restrict__ out)
{
    __shared__ float vf[kC * kNB];    // 120 floats
    if (threadIdx.x < kC * kNB) vf[threadIdx.x] = val_freqs[threadIdx.x];
    __syncthreads();

    long long g = (long long)blockIdx.x * blockDim.x + threadIdx.x;
    const long long ngroups = (long long)kB * kG;   // 1,048,576
    if (g >= ngroups) return;
    const int b  = (int)(g / kG);
    const int s4 = (int)(g % kG);

    const float4* __restrict__ lg4  = reinterpret_cast<const float4*>(logits);
    float4* __restrict__       out4 = reinterpret_cast<float4*>(out);

    // 4 pixels x 8 classes; class planes contiguous -> coalesced 16B/lane
    float4 l[kC];
#pragma unroll
    for (int c = 0; c < kC; ++c)
        l[c] = lg4[(long long)(b * kC + c) * kG + s4];

    float4 o[kC];
#pragma unroll
    for (int px = 0; px < 4; ++px) {
        float lx[kC];
#pragma unroll
        for (int c = 0; c < kC; ++c)
            lx[c] = reinterpret_cast<const float*>(&l[c])[px];

        // ---- numpy-f32 pipeline replica ----
        // max over classes (exact)
        float m = lx[0];
#pragma unroll
        for (int c = 1; c < kC; ++c) m = fmaxf(m, lx[c]);

        // e = np.exp(x - m)  (f32 sub, numpy SIMD exp replica)
        float e[kC];
#pragma unroll
        for (int c = 0; c < kC; ++c)
            e[c] = np_expf(lx[c] - m);

        // s = np.sum(e, axis=class): numpy reduces a strided axis
        // plane-sequentially: ((((((e0+e1)+e2)+e3)+e4)+e5)+e6)+e7 in f32.
        float s = e[0];
#pragma unroll
        for (int c = 1; c < kC; ++c) s = s + e[c];

        // p = e / s (IEEE f32 div); p15 = p * 15.0f; bin = clip(int(floor(p15)))
        int bi[kC];
#pragma unroll
        for (int c = 0; c < kC; ++c) {
            float p   = e[c] / s;
            float p15 = p * 15.0f;
            int bb = (int)floorf(p15);
            bi[c] = bb < 0 ? 0 : (bb > kNB - 1 ? kNB - 1 : bb);
        }

        // gather + renormalize (sequential sum, IEEE div) — all f32, as numpy
        float calv[kC];
#pragma unroll
        for (int c = 0; c < kC; ++c)
            calv[c] = vf[c * kNB + bi[c]];
        float csum = calv[0];
#pragma unroll
        for (int c = 1; c < kC; ++c) csum = csum + calv[c];
#pragma unroll
        for (int c = 0; c < kC; ++c)
            reinterpret_cast<float*>(&o[c])[px] = calv[c] / csum;
    }

#pragma unroll
    for (int c = 0; c < kC; ++c)
        out4[(long long)(b * kC + c) * kG + s4] = o[c];
}

extern "C" void kernel_launch(void* const* d_in, const int* in_sizes, int n_in,
                              void* d_out, int out_size, void* d_ws, size_t ws_size,
                              hipStream_t stream) {
    const float* logits    = (const float*)d_in[0];
    const float* val_freqs = (const float*)d_in[1];
    float* out = (float*)d_out;

    const long long ngroups = (long long)kB * kG;   // 1,048,576 threads
    const int block = 256;
    const int grid  = (int)((ngroups + block - 1) / block);   // 4096
    hist_calib_kernel<<<grid, block, 0, stream>>>(logits, val_freqs, out);
}